// Round 17
// baseline (232.753 us; speedup 1.0000x reference)
//
#include <hip/hip_runtime.h>
#include <stdint.h>

typedef __attribute__((ext_vector_type(4))) float          f32x4;
typedef __attribute__((ext_vector_type(8))) short          bf16x8;
typedef __attribute__((ext_vector_type(8))) unsigned short u16x8;
typedef __attribute__((ext_vector_type(4))) unsigned short u16x4;
typedef __attribute__((ext_vector_type(2))) long           longx2;

static __device__ __forceinline__ unsigned short f2bf(float f){
  uint32_t u = __builtin_bit_cast(uint32_t, f);
  u += 0x7FFFu + ((u >> 16) & 1u);          // RNE
  return (unsigned short)(u >> 16);
}

// ---- f32 -> OCP e4m3fn (software fallback; HW cvt_pk used when available) --
static __device__ __forceinline__ uint32_t f2e4m3(float x){
  uint32_t u = __builtin_bit_cast(uint32_t, x);
  uint32_t s = (u >> 24) & 0x80u;
  uint32_t a = u & 0x7FFFFFFFu;
  if (a >= 0x43E00000u) return s | 0x7Eu;
  int ebits = (int)(a >> 23);
  uint32_t mfull = (a & 0x7FFFFFu) | 0x800000u;
  int shift = (ebits >= 121) ? 20 : 20 + (121 - ebits);
  if (shift > 31) return s;
  uint32_t q = mfull >> shift;
  uint32_t rem = mfull & ((1u << shift) - 1u);
  uint32_t half = 1u << (shift - 1);
  q += (rem > half || (rem == half && (q & 1u)));
  if (ebits >= 121){
    uint32_t E = (uint32_t)(ebits - 121 + 1);
    if (q == 16u){ E += 1u; q = 8u; }
    uint32_t man = q - 8u;
    if (E > 15u || (E == 15u && man == 7u)) return s | 0x7Eu;
    return s | (E << 3) | man;
  } else {
    if (q >= 8u) return s | (1u << 3) | (q - 8u);
    return s | q;
  }
}
static __device__ __forceinline__ uint32_t pk4_e4m3(float a0, float a1, float a2, float a3){
#if __has_builtin(__builtin_amdgcn_cvt_pk_fp8_f32)
  uint32_t pk = (uint32_t)__builtin_amdgcn_cvt_pk_fp8_f32(a0, a1, 0, false);
  pk = (uint32_t)__builtin_amdgcn_cvt_pk_fp8_f32(a2, a3, (int)pk, true);
  return pk;
#else
  return f2e4m3(a0) | (f2e4m3(a1) << 8) | (f2e4m3(a2) << 16) | (f2e4m3(a3) << 24);
#endif
}

#define GLL(SRC, DST) __builtin_amdgcn_global_load_lds(                         \
    (const __attribute__((address_space(1))) unsigned int*)(SRC),               \
    (__attribute__((address_space(3))) unsigned int*)(DST), 16, 0, 0)

// ========== k_pre: merged preprocessing (cvt + tconv + cvtwv) ===============
__global__ void k_pre(const float* __restrict__ x, const float* __restrict__ wqkv,
                      const float* __restrict__ wproj,
                      unsigned short* __restrict__ xbf, unsigned char* __restrict__ x8,
                      unsigned char* __restrict__ WT8, unsigned short* __restrict__ WpT,
                      unsigned short* __restrict__ WvB)
{
  __shared__ float tl[64][65];
  const int bx = blockIdx.x, t = threadIdx.x;
  if (bx < 12288){
    const long i = ((long)bx * 256 + t) * 8;
    const f32x4* p = (const f32x4*)(x + i);
    f32x4 a = p[0], b = p[1];
    u16x8 o;
    #pragma unroll
    for (int j = 0; j < 4; j++){ o[j] = f2bf(a[j]); o[4+j] = f2bf(b[j]); }
    *(u16x8*)(xbf + i) = o;
    *(uint32_t*)(x8 + i)     = pk4_e4m3(a[0], a[1], a[2], a[3]);
    *(uint32_t*)(x8 + i + 4) = pk4_e4m3(b[0], b[1], b[2], b[3]);
  } else if (bx < 12720){
    const int idx = bx - 12288;
    const int cb = idx % 36, rb = idx / 36;
    const int qk = (cb < 24);
    const float* in = qk ? wqkv : wproj;
    const int C = qk ? 2304 : 768;
    const int c0 = (qk ? cb : cb - 24) * 64, r0 = rb * 64;
    {
      const int lr = t >> 2, lc = (t & 3) * 16;
      const f32x4* s = (const f32x4*)(in + (long)(r0 + lr) * C + c0 + lc);
      #pragma unroll
      for (int q = 0; q < 4; q++){
        f32x4 v = s[q];
        #pragma unroll
        for (int j = 0; j < 4; j++) tl[lr][lc + q*4 + j] = v[j];
      }
    }
    __syncthreads();
    {
      const int oc = t >> 2, orr = (t & 3) * 16;
      if (qk){
        uint32_t w0 = pk4_e4m3(tl[orr+0][oc],  tl[orr+1][oc],  tl[orr+2][oc],  tl[orr+3][oc]);
        uint32_t w1 = pk4_e4m3(tl[orr+4][oc],  tl[orr+5][oc],  tl[orr+6][oc],  tl[orr+7][oc]);
        uint32_t w2 = pk4_e4m3(tl[orr+8][oc],  tl[orr+9][oc],  tl[orr+10][oc], tl[orr+11][oc]);
        uint32_t w3 = pk4_e4m3(tl[orr+12][oc], tl[orr+13][oc], tl[orr+14][oc], tl[orr+15][oc]);
        uint32_t* d = (uint32_t*)(WT8 + (long)(c0 + oc) * 768 + r0 + orr);
        d[0] = w0; d[1] = w1; d[2] = w2; d[3] = w3;
      } else {
        u16x8 o0, o1;
        #pragma unroll
        for (int i = 0; i < 8; i++){ o0[i] = f2bf(tl[orr + i][oc]); o1[i] = f2bf(tl[orr + 8 + i][oc]); }
        u16x8* dst = (u16x8*)(WpT + (long)(c0 + oc) * 768 + r0 + orr);
        dst[0] = o0; dst[1] = o1;
      }
    }
  } else {
    const long idx = ((long)(bx - 12720) * 256 + t) * 8;
    const int e = (int)(idx / 768), hd = (int)(idx - (long)e * 768);
    const float* s = wqkv + (long)e * 2304 + 1536 + hd;
    f32x4 a = *(const f32x4*)s, b = *(const f32x4*)(s + 4);
    u16x8 o;
    #pragma unroll
    for (int j = 0; j < 4; j++){ o[j] = f2bf(a[j]); o[4+j] = f2bf(b[j]); }
    *(u16x8*)(WvB + idx) = o;
  }
}

// ===================== fragment reads (conflict-free swizzle) ===============
static __device__ __forceinline__ bf16x8 ldfrag(const char* slot, int row, int ko){
  const int k2 = (ko ^ (row >> 1)) & 3;
  return *(const bf16x8*)(slot + row*64 + k2*16);
}
static __device__ __forceinline__ longx2 ldfrag8(const char* slot, int row, int ko){
  const int k2 = (ko ^ (row >> 1)) & 3;
  return *(const longx2*)(slot + row*64 + k2*16);
}

// ========== k_gemm256: fp8-input 256x256, 24-phase counted-vmcnt ============
static __device__ __forceinline__ void stg8(const unsigned char* __restrict__ G, int row0, int keB,
                                            char* lds_slot, int t){
  #pragma unroll
  for (int l = 0; l < 2; l++){
    const int r = l*128 + (t >> 2);
    const int c = (t & 3) ^ ((r >> 1) & 3);
    GLL((const char*)(G + (long)(row0 + r) * 768 + keB + c * 16),
        lds_slot + l*8192 + (t & 0x1C0) * 16);
  }
}

#define PH8(BUF, KK, MH, STAGE_STMT, WAIT_STMT) do {                           \
    longx2 af[4];                                                              \
    if (MH == 0) {                                                             \
      _Pragma("unroll")                                                        \
      for (int ni = 0; ni < 4; ni++)                                           \
        bq[ni] = ldfrag8(sB[BUF][KK], wn*64 + ni*16 + arow, ko);               \
    }                                                                          \
    _Pragma("unroll")                                                          \
    for (int mi = 0; mi < 4; mi++)                                             \
      af[mi] = ldfrag8(sA[BUF][KK], wm*128 + MH*64 + mi*16 + arow, ko);        \
    __builtin_amdgcn_s_barrier();                                              \
    __builtin_amdgcn_s_setprio(1);                                             \
    _Pragma("unroll")                                                          \
    for (int mi = 0; mi < 4; mi++)                                             \
      _Pragma("unroll")                                                        \
      for (int ni = 0; ni < 4; ni++){                                          \
        acc[MH*4+mi][ni] = __builtin_amdgcn_mfma_f32_16x16x32_fp8_fp8(         \
            af[mi][0], bq[ni][0], acc[MH*4+mi][ni], 0, 0, 0);                  \
        acc[MH*4+mi][ni] = __builtin_amdgcn_mfma_f32_16x16x32_fp8_fp8(         \
            af[mi][1], bq[ni][1], acc[MH*4+mi][ni], 0, 0, 0);                  \
      }                                                                        \
    __builtin_amdgcn_s_setprio(0);                                             \
    STAGE_STMT;                                                                \
    WAIT_STMT;                                                                 \
    __builtin_amdgcn_s_barrier();                                              \
  } while(0)

__global__ __launch_bounds__(512, 2)
void k_gemm256(const unsigned char* __restrict__ A8, const unsigned char* __restrict__ BT8,
               unsigned char* __restrict__ QT8, unsigned char* __restrict__ KT8,
               float* __restrict__ nrmp)
{
  __shared__ __attribute__((aligned(16))) char lds[131072];
  const int o  = blockIdx.x;
  const int wg = (o & 7) * 96 + (o >> 3);          // bijective XCD swizzle, 768 wgs
  const int jt = wg % 6, mt = wg / 6;
  const int m0 = mt * 256, j0 = jt * 256;
  const int t = threadIdx.x, lane = t & 63, w = t >> 6;
  const int wm = w >> 2, wn = w & 3;
  const int arow = lane & 15, ko = lane >> 4;

  char* const sA[2][2] = {{lds,           lds + 16384},
                          {lds + 65536,   lds + 65536 + 16384}};
  char* const sB[2][2] = {{lds + 32768,   lds + 49152},
                          {lds + 65536 + 32768, lds + 65536 + 49152}};

  f32x4 acc[8][4] = {};

  stg8(BT8, j0, 0,   sB[0][0], t);
  stg8(A8,  m0, 0,   sA[0][0], t);
  stg8(BT8, j0, 64,  sB[0][1], t);
  stg8(A8,  m0, 64,  sA[0][1], t);
  stg8(BT8, j0, 128, sB[1][0], t);
  stg8(A8,  m0, 128, sA[1][0], t);
  stg8(BT8, j0, 192, sB[1][1], t);
  asm volatile("s_waitcnt vmcnt(6)" ::: "memory");
  __builtin_amdgcn_s_barrier();

  #pragma unroll 1
  for (int it = 0; it < 3; ++it){
    const int t1 = 2*it + 1, t2 = 2*it + 2, t3 = 2*it + 3;
    longx2 bq[4];
    PH8(0,0,0, { stg8(A8, m0, t1*128+64, sA[1][1], t); }, ;);
    PH8(0,0,1, { if (t2 < 6) stg8(BT8, j0, t2*128,    sB[0][0], t); }, ;);
    PH8(0,1,0, { if (t2 < 6) stg8(A8,  m0, t2*128,    sA[0][0], t); }, ;);
    PH8(0,1,1, { if (t2 < 6) stg8(BT8, j0, t2*128+64, sB[0][1], t); },
               { if (it == 2) asm volatile("s_waitcnt vmcnt(0)" ::: "memory");
                 else         asm volatile("s_waitcnt vmcnt(6)" ::: "memory"); });
    PH8(1,0,0, { if (t2 < 6) stg8(A8,  m0, t2*128+64, sA[0][1], t); }, ;);
    PH8(1,0,1, { if (t3 < 6) stg8(BT8, j0, t3*128,    sB[1][0], t); }, ;);
    PH8(1,1,0, { if (t3 < 6) stg8(A8,  m0, t3*128,    sA[1][0], t); }, ;);
    PH8(1,1,1, { if (t3 < 6) stg8(BT8, j0, t3*128+64, sB[1][1], t); },
               { if (it == 2) asm volatile("s_waitcnt vmcnt(0)" ::: "memory");
                 else         asm volatile("s_waitcnt vmcnt(6)" ::: "memory"); });
  }

  const int b = m0 >> 12;
  const int chunk = ((m0 & 4095) >> 7) + wm;
  #pragma unroll
  for (int ni = 0; ni < 4; ni++){
    float ss = 0.f;
    #pragma unroll
    for (int mi = 0; mi < 8; mi++)
      #pragma unroll
      for (int r = 0; r < 4; r++) ss += acc[mi][ni][r] * acc[mi][ni][r];
    ss += __shfl_xor(ss, 16);
    ss += __shfl_xor(ss, 32);
    if (lane < 16){
      const int jc = j0 + wn*64 + ni*16 + lane;
      const int s  = (jc >= 768);
      const int jl = jc - s * 768;
      const int h  = jl / 48;
      const int c  = jl - h * 48;
      nrmp[(long)(s*6144 + (b*16 + h)*48 + c)*32 + chunk] = ss;
    }
  }
  #pragma unroll
  for (int mi = 0; mi < 8; mi++){
    #pragma unroll
    for (int ni = 0; ni < 4; ni++){
      const int j  = wn*64 + ni*16 + (lane & 15);
      const int nl = wm*128 + mi*16 + (lane >> 4)*4;
      uint32_t pk = pk4_e4m3(acc[mi][ni][0], acc[mi][ni][1], acc[mi][ni][2], acc[mi][ni][3]);
      const int d = (nl >> 2) ^ ((j & 15) << 2);
      *(uint32_t*)(lds + (long)j*256 + (d << 2)) = pk;
    }
  }
  __syncthreads();
  for (int rr = 0; rr < 32; rr++){
    const int j  = w*32 + rr;
    const int jc = j0 + j;
    const int s  = (jc >= 768);
    const int jl = jc - s * 768;
    const int h  = jl / 48;
    const int c  = jl - h * 48;
    const int dp = lane ^ ((j & 15) << 2);
    uint32_t v = *(const uint32_t*)(lds + (long)j*256 + (dp << 2));
    *(uint32_t*)((s ? KT8 : QT8) + ((long)((b*16 + h)*48 + c) << 12) + (m0 & 4095) + lane*4) = v;
  }
}

// =========== shared bf16 ring-3 machinery (gemmP / comb) ====================
static __device__ __forceinline__ void stageA512(const unsigned short* __restrict__ G, int row0, int ke,
                                                 char* slot, int t){
  const int r  = t >> 2;
  const int k2 = (t & 3) ^ ((r >> 1) & 3);
  GLL((const char*)(G + (long)(row0 + r) * 768 + ke + k2 * 8), slot + (t & 0x1C0) * 16);
}
static __device__ __forceinline__ void stageB512(const unsigned short* __restrict__ G, int row0, int ke,
                                                 char* slot, int t){
  #pragma unroll
  for (int l = 0; l < 2; l++){
    const int r  = l*128 + (t >> 2);
    const int k2 = (t & 3) ^ ((r >> 1) & 3);
    GLL((const char*)(G + (long)(row0 + r) * 768 + ke + k2 * 8), slot + l*8192 + (t & 0x1C0) * 16);
  }
}
// 256-thread stager for 128 rows (comb): 2 loads/thread
static __device__ __forceinline__ void stg128c(const unsigned short* __restrict__ G, int row0, int ke,
                                               char* slot, int t){
  #pragma unroll
  for (int l = 0; l < 2; l++){
    const int r  = ((l*4 + (t >> 6)) << 4) + ((t & 63) >> 2);
    const int k2 = (t & 3) ^ ((r >> 1) & 3);
    GLL((const char*)(G + (long)(row0 + r) * 768 + ke + k2 * 8),
        slot + l*4096 + (t & 0x3C0) * 16);
  }
}

#define VM0 asm volatile("s_waitcnt vmcnt(0)" ::: "memory")
#define VM3 asm volatile("s_waitcnt vmcnt(3)" ::: "memory")
#define VM4 asm volatile("s_waitcnt vmcnt(4)" ::: "memory")

#define PHASE1(CUR, STAGE_STMT, WAIT_STMT) do {                                \
    bf16x8 af[4], bq[4];                                                       \
    _Pragma("unroll")                                                          \
    for (int ni = 0; ni < 4; ni++)                                             \
      bq[ni] = ldfrag(sB[CUR], wn*64 + ni*16 + arow, ko);                      \
    _Pragma("unroll")                                                          \
    for (int mi = 0; mi < 4; mi++)                                             \
      af[mi] = ldfrag(sA[CUR], wm64 + mi*16 + arow, ko);                       \
    __builtin_amdgcn_s_barrier();                                              \
    __builtin_amdgcn_s_setprio(1);                                             \
    _Pragma("unroll")                                                          \
    for (int mi = 0; mi < 4; mi++)                                             \
      _Pragma("unroll")                                                        \
      for (int ni = 0; ni < 4; ni++)                                           \
        acc[mi][ni] = __builtin_amdgcn_mfma_f32_16x16x32_bf16(                 \
            af[mi], bq[ni], acc[mi][ni], 0, 0, 0);                             \
    __builtin_amdgcn_s_setprio(0);                                             \
    STAGE_STMT;                                                                \
    WAIT_STMT;                                                                 \
    __builtin_amdgcn_s_barrier();                                              \
  } while(0)

// ===== k_gemmP: 128x256 BK=32 ring-3 (proven), x_bf @ WcombT_b -> outF ======
__global__ __launch_bounds__(512, 4)
void k_gemmP(const unsigned short* __restrict__ A, const unsigned short* __restrict__ BT,
             float* __restrict__ OUTF, const float* __restrict__ bias)
{
  __shared__ __attribute__((aligned(16))) char lds[73728];
  const int o  = blockIdx.x;
  const int wg = (o & 7) * 96 + (o >> 3);                  // 768 wgs
  const int jt = wg % 3, mt = wg / 3;
  const int m0 = mt * 128, j0 = jt * 256;
  const int t = threadIdx.x, lane = t & 63, w = t >> 6;
  const int wm = w >> 2, wn = w & 3;
  const int wm64 = wm * 64;
  const int arow = lane & 15, ko = lane >> 4;
  const unsigned short* BTb = BT + ((long)(m0 >> 12)) * 589824;

  char* const sA[3] = {lds,          lds + 8192,          lds + 16384};
  char* const sB[3] = {lds + 24576,  lds + 24576 + 16384, lds + 24576 + 32768};

  f32x4 acc[4][4] = {};

  stageA512(A, m0, 0,  sA[0], t);  stageB512(BTb, j0, 0,  sB[0], t);
  stageA512(A, m0, 32, sA[1], t);  stageB512(BTb, j0, 32, sB[1], t);
  VM3;
  __builtin_amdgcn_s_barrier();

  #pragma unroll 1
  for (int g = 0; g < 7; ++g){
    const int kb = g * 96;
    PHASE1(0, { stageA512(A, m0, kb+64,  sA[2], t); stageB512(BTb, j0, kb+64,  sB[2], t); }, VM3);
    PHASE1(1, { stageA512(A, m0, kb+96,  sA[0], t); stageB512(BTb, j0, kb+96,  sB[0], t); }, VM3);
    PHASE1(2, { stageA512(A, m0, kb+128, sA[1], t); stageB512(BTb, j0, kb+128, sB[1], t); }, VM3);
  }
  PHASE1(0, { stageA512(A, m0, 736, sA[2], t); stageB512(BTb, j0, 736, sB[2], t); }, VM3);
  PHASE1(1, { ; }, VM0);
  PHASE1(2, { ; }, ;);

  #pragma unroll
  for (int mi = 0; mi < 4; mi++){
    #pragma unroll
    for (int ni = 0; ni < 4; ni++){
      const int jc = j0 + wn*64 + ni*16 + (lane & 15);
      const float bv = bias[jc];
      const long mr = (long)m0 + wm64 + mi*16 + (lane >> 4)*4;
      #pragma unroll
      for (int r = 0; r < 4; r++) OUTF[(mr + r) * 768 + jc] = acc[mi][ni][r] + bv;
    }
  }
}

// == k_attn_part (fused): S partials + last-block softmax + wmod per bh ======
__global__ __launch_bounds__(256)
void k_attn_part(const unsigned char* __restrict__ QT8, const unsigned char* __restrict__ KT8,
                 float* __restrict__ Spart, const float* __restrict__ nrmp,
                 const unsigned short* __restrict__ WpT, const float* __restrict__ temp,
                 unsigned short* __restrict__ WmodT, int* __restrict__ cnt)
{
  __shared__ float Sl[4][2304];
  __shared__ float invq_s[48], invk_s[48];
  __shared__ int lastf;
  const int bh = blockIdx.x, ksp = blockIdx.y;
  const int t = threadIdx.x, lane = t & 63, w = t >> 6;
  const unsigned char* qb = QT8 + ((long)bh * 48 << 12);
  const unsigned char* kb = KT8 + ((long)bh * 48 << 12);
  const int n00 = ksp * 1024 + w * 256;
  f32x4 acc[3][3] = {};
  for (int kt = 0; kt < 256; kt += 32){
    long af[3], bfr[3];
    #pragma unroll
    for (int ci = 0; ci < 3; ci++)
      af[ci]  = *(const long*)(qb + ((long)(ci*16 + (lane & 15)) << 12) + n00 + kt + (lane >> 4) * 8);
    #pragma unroll
    for (int di = 0; di < 3; di++)
      bfr[di] = *(const long*)(kb + ((long)(di*16 + (lane & 15)) << 12) + n00 + kt + (lane >> 4) * 8);
    #pragma unroll
    for (int ci = 0; ci < 3; ci++)
      #pragma unroll
      for (int di = 0; di < 3; di++)
        acc[ci][di] = __builtin_amdgcn_mfma_f32_16x16x32_fp8_fp8(af[ci], bfr[di], acc[ci][di], 0, 0, 0);
  }
  #pragma unroll
  for (int ci = 0; ci < 3; ci++)
    #pragma unroll
    for (int di = 0; di < 3; di++)
      #pragma unroll
      for (int r = 0; r < 4; r++)
        Sl[w][(ci*16 + (lane >> 4)*4 + r) * 48 + di*16 + (lane & 15)] = acc[ci][di][r];
  __syncthreads();
  float* outp = Spart + ((long)ksp * 128 + bh) * 2304;
  for (int idx = t; idx < 2304; idx += 256)
    outp[idx] = Sl[0][idx] + Sl[1][idx] + Sl[2][idx] + Sl[3][idx];

  // ---- finisher election: last of the 4 ksp blocks for this bh ----
  if (t == 0){
    __threadfence();
    lastf = (atomicAdd(&cnt[bh], 1) == 3);
  }
  __syncthreads();
  if (!lastf) return;
  __threadfence();

  const int h = bh & 15;
  unsigned short* aT = (unsigned short*)&Sl[0][0];   // [48 d][64 c] bf16, reuse LDS
  if (t < 48){
    float sq = 0.f, sk = 0.f;
    const float* pq = nrmp + (long)(bh*48 + t) * 32;
    const float* pk = nrmp + (long)(6144 + bh*48 + t) * 32;
    #pragma unroll
    for (int i = 0; i < 32; i++){ sq += pq[i]; sk += pk[i]; }
    invq_s[t] = 1.0f / fmaxf(sqrtf(sq), 1e-12f);
    invk_s[t] = 1.0f / fmaxf(sqrtf(sk), 1e-12f);
  }
  __syncthreads();
  if (t < 48){
    const int c = t;
    const float scq = invq_s[c] * temp[h];
    float row[48];
    #pragma unroll
    for (int d = 0; d < 48; d++){
      long base = ((long)bh * 48 + c) * 48 + d;
      float v = Spart[base] + Spart[base + 128L*2304] + Spart[base + 256L*2304] + Spart[base + 384L*2304];
      row[d] = v * scq * invk_s[d];
    }
    float mx = -1e30f;
    #pragma unroll
    for (int d = 0; d < 48; d++) mx = fmaxf(mx, row[d]);
    float s = 0.f;
    #pragma unroll
    for (int d = 0; d < 48; d++){ row[d] = expf(row[d] - mx); s += row[d]; }
    const float inv = 1.0f / s;
    #pragma unroll
    for (int d = 0; d < 48; d++) aT[d*64 + c] = f2bf(row[d] * inv);
    u16x8 z = {};
    *(u16x8*)(aT + c*64 + 48) = z;
    *(u16x8*)(aT + c*64 + 56) = z;
  }
  __syncthreads();
  // wmod for this bh: WmodT[b][j][h*48+d], 4 waves x 192 j-rows
  const unsigned short* wp = WpT + h * 48;
  unsigned short* wmb = WmodT + (long)(bh >> 4) * 589824;
  #pragma unroll 1
  for (int ch = 0; ch < 3; ch++){
    f32x4 a2[4][3] = {};
    #pragma unroll
    for (int kt = 0; kt < 64; kt += 32){
      bf16x8 bfr2[3];
      #pragma unroll
      for (int ni = 0; ni < 3; ni++)
        bfr2[ni] = *(const bf16x8*)(aT + (ni*16 + (lane & 15))*64 + kt + (lane >> 4)*8);
      #pragma unroll
      for (int mi = 0; mi < 4; mi++){
        const int j = w*192 + ch*64 + mi*16 + (lane & 15);
        bf16x8 a = *(const bf16x8*)(wp + (long)j*768 + kt + (lane >> 4)*8);
        #pragma unroll
        for (int ni = 0; ni < 3; ni++)
          a2[mi][ni] = __builtin_amdgcn_mfma_f32_16x16x32_bf16(a, bfr2[ni], a2[mi][ni], 0, 0, 0);
      }
    }
    #pragma unroll
    for (int mi = 0; mi < 4; mi++)
      #pragma unroll
      for (int ni = 0; ni < 3; ni++)
        #pragma unroll
        for (int r = 0; r < 4; r++){
          const int j = w*192 + ch*64 + mi*16 + (lane >> 4)*4 + r;
          const int d = ni*16 + (lane & 15);
          wmb[(long)j*768 + h*48 + d] = f2bf(a2[mi][ni][r]);
        }
  }
}

// --- k_comb (ring-3): WcombT[row][e] = WmodT[row][hd] @ WvB[e][hd] ----------
__global__ __launch_bounds__(256, 3)
void k_comb(const unsigned short* __restrict__ A, const unsigned short* __restrict__ BT,
            unsigned short* __restrict__ OUT)
{
  __shared__ __attribute__((aligned(16))) char lds[49152];
  const int m0 = blockIdx.y * 128;
  const int j0 = blockIdx.x * 128;
  const int t = threadIdx.x, lane = t & 63, w = t >> 6;
  const int wm = w >> 1, wn = w & 1;
  const int wm64 = wm * 64;
  const int arow = lane & 15, ko = lane >> 4;

  char* const sA[3] = {lds,          lds + 8192,   lds + 16384};
  char* const sB[3] = {lds + 24576,  lds + 32768,  lds + 40960};

  f32x4 acc[4][4] = {};

  stg128c(A, m0, 0,  sA[0], t);  stg128c(BT, j0, 0,  sB[0], t);
  stg128c(A, m0, 32, sA[1], t);  stg128c(BT, j0, 32, sB[1], t);
  VM4;
  __builtin_amdgcn_s_barrier();

  #pragma unroll 1
  for (int g = 0; g < 7; ++g){
    const int kb = g * 96;
    PHASE1(0, { stg128c(A, m0, kb+64,  sA[2], t); stg128c(BT, j0, kb+64,  sB[2], t); }, VM4);
    PHASE1(1, { stg128c(A, m0, kb+96,  sA[0], t); stg128c(BT, j0, kb+96,  sB[0], t); }, VM4);
    PHASE1(2, { stg128c(A, m0, kb+128, sA[1], t); stg128c(BT, j0, kb+128, sB[1], t); }, VM4);
  }
  PHASE1(0, { stg128c(A, m0, 736, sA[2], t); stg128c(BT, j0, 736, sB[2], t); }, VM4);
  PHASE1(1, { ; }, VM0);
  PHASE1(2, { ; }, ;);

  #pragma unroll
  for (int mi = 0; mi < 4; mi++)
    #pragma unroll
    for (int ni = 0; ni < 4; ni++){
      const int jc = j0 + wn*64 + ni*16 + (lane & 15);
      const long mr = (long)m0 + wm64 + mi*16 + (lane >> 4) * 4;
      #pragma unroll
      for (int r = 0; r < 4; r++) OUT[(mr + r) * 768 + jc] = f2bf(acc[mi][ni][r]);
    }
}

extern "C" void kernel_launch(void* const* d_in, const int* in_sizes, int n_in,
                              void* d_out, int out_size, void* d_ws, size_t ws_size,
                              hipStream_t stream)
{
  (void)in_sizes; (void)n_in; (void)out_size; (void)ws_size;
  const float* x      = (const float*)d_in[0];
  const float* w_qkv  = (const float*)d_in[1];
  const float* temp   = (const float*)d_in[2];
  const float* w_proj = (const float*)d_in[3];
  const float* b_proj = (const float*)d_in[4];
  float* outF = (float*)d_out;

  char* ws = (char*)d_ws;
  size_t off = 0;
  auto alloc = [&](size_t bytes)->char*{ char* p = ws + off; off += (bytes + 255) & ~(size_t)255; return p; };

  unsigned short* x_bf  = (unsigned short*)alloc(50331648);           // [32768][768] bf16
  unsigned char*  x8    = (unsigned char*)alloc(25165824);            // [32768][768] e4m3
  unsigned char*  WT8   = (unsigned char*)alloc(1179648);             // [1536 q||k][768] e4m3
  unsigned short* WpT   = (unsigned short*)alloc(1179648);            // [768][768] bf16
  unsigned short* WvB   = (unsigned short*)alloc(1179648);            // [768 e][768 hd] bf16
  unsigned char*  QT8   = (unsigned char*)alloc(50331648);            // QT||KT [12288][4096] fp8
  unsigned char*  KT8   = QT8 + (long)6144 * 4096;
  float* nrmp           = (float*)alloc(12288L * 32 * 4);             // [12288 rows][32 chunks] f32
  float* Spart          = (float*)alloc(4L * 128 * 2304 * 4);         // [4][128][48][48] f32
  unsigned short* WmodT = (unsigned short*)alloc(9437184);            // [8][768 j][768 hd] bf16
  unsigned short* WcombT= (unsigned short*)alloc(9437184);            // [8][768 j][768 e] bf16
  int* cnt              = (int*)alloc(512);                           // [128] finisher counters

  hipMemsetAsync(cnt, 0, 512, stream);
  k_pre<<<13008, 256, 0, stream>>>(x, w_qkv, w_proj, x_bf, x8, WT8, WpT, WvB);
  k_gemm256<<<768, 512, 0, stream>>>(x8, WT8, QT8, KT8, nrmp);
  k_attn_part<<<dim3(128, 4), 256, 0, stream>>>(QT8, KT8, Spart, nrmp, WpT, temp, WmodT, cnt);
  k_comb<<<dim3(6, 48), 256, 0, stream>>>(WmodT, WvB, WcombT);
  k_gemmP<<<768, 512, 0, stream>>>(x_bf, WcombT, outF, b_proj);
}

// Round 18
// 208.845 us; speedup vs baseline: 1.1145x; 1.1145x over previous
//
#include <hip/hip_runtime.h>
#include <stdint.h>

typedef __attribute__((ext_vector_type(4))) float          f32x4;
typedef __attribute__((ext_vector_type(8))) short          bf16x8;
typedef __attribute__((ext_vector_type(8))) unsigned short u16x8;
typedef __attribute__((ext_vector_type(4))) unsigned short u16x4;
typedef __attribute__((ext_vector_type(2))) long           longx2;

static __device__ __forceinline__ unsigned short f2bf(float f){
  uint32_t u = __builtin_bit_cast(uint32_t, f);
  u += 0x7FFFu + ((u >> 16) & 1u);          // RNE
  return (unsigned short)(u >> 16);
}

// ---- f32 -> OCP e4m3fn (software fallback; HW cvt_pk used when available) --
static __device__ __forceinline__ uint32_t f2e4m3(float x){
  uint32_t u = __builtin_bit_cast(uint32_t, x);
  uint32_t s = (u >> 24) & 0x80u;
  uint32_t a = u & 0x7FFFFFFFu;
  if (a >= 0x43E00000u) return s | 0x7Eu;
  int ebits = (int)(a >> 23);
  uint32_t mfull = (a & 0x7FFFFFu) | 0x800000u;
  int shift = (ebits >= 121) ? 20 : 20 + (121 - ebits);
  if (shift > 31) return s;
  uint32_t q = mfull >> shift;
  uint32_t rem = mfull & ((1u << shift) - 1u);
  uint32_t half = 1u << (shift - 1);
  q += (rem > half || (rem == half && (q & 1u)));
  if (ebits >= 121){
    uint32_t E = (uint32_t)(ebits - 121 + 1);
    if (q == 16u){ E += 1u; q = 8u; }
    uint32_t man = q - 8u;
    if (E > 15u || (E == 15u && man == 7u)) return s | 0x7Eu;
    return s | (E << 3) | man;
  } else {
    if (q >= 8u) return s | (1u << 3) | (q - 8u);
    return s | q;
  }
}
static __device__ __forceinline__ uint32_t pk4_e4m3(float a0, float a1, float a2, float a3){
#if __has_builtin(__builtin_amdgcn_cvt_pk_fp8_f32)
  uint32_t pk = (uint32_t)__builtin_amdgcn_cvt_pk_fp8_f32(a0, a1, 0, false);
  pk = (uint32_t)__builtin_amdgcn_cvt_pk_fp8_f32(a2, a3, (int)pk, true);
  return pk;
#else
  return f2e4m3(a0) | (f2e4m3(a1) << 8) | (f2e4m3(a2) << 16) | (f2e4m3(a3) << 24);
#endif
}

#define GLL(SRC, DST) __builtin_amdgcn_global_load_lds(                         \
    (const __attribute__((address_space(1))) unsigned int*)(SRC),               \
    (__attribute__((address_space(3))) unsigned int*)(DST), 16, 0, 0)

// ========== k_pre: merged preprocessing (cvt + tconv + cvtwv) ===============
__global__ void k_pre(const float* __restrict__ x, const float* __restrict__ wqkv,
                      const float* __restrict__ wproj,
                      unsigned short* __restrict__ xbf, unsigned char* __restrict__ x8,
                      unsigned char* __restrict__ WT8, unsigned short* __restrict__ WpT,
                      unsigned short* __restrict__ WvB)
{
  __shared__ float tl[64][65];
  const int bx = blockIdx.x, t = threadIdx.x;
  if (bx < 12288){
    const long i = ((long)bx * 256 + t) * 8;
    const f32x4* p = (const f32x4*)(x + i);
    f32x4 a = p[0], b = p[1];
    u16x8 o;
    #pragma unroll
    for (int j = 0; j < 4; j++){ o[j] = f2bf(a[j]); o[4+j] = f2bf(b[j]); }
    *(u16x8*)(xbf + i) = o;
    *(uint32_t*)(x8 + i)     = pk4_e4m3(a[0], a[1], a[2], a[3]);
    *(uint32_t*)(x8 + i + 4) = pk4_e4m3(b[0], b[1], b[2], b[3]);
  } else if (bx < 12720){
    const int idx = bx - 12288;
    const int cb = idx % 36, rb = idx / 36;
    const int qk = (cb < 24);
    const float* in = qk ? wqkv : wproj;
    const int C = qk ? 2304 : 768;
    const int c0 = (qk ? cb : cb - 24) * 64, r0 = rb * 64;
    {
      const int lr = t >> 2, lc = (t & 3) * 16;
      const f32x4* s = (const f32x4*)(in + (long)(r0 + lr) * C + c0 + lc);
      #pragma unroll
      for (int q = 0; q < 4; q++){
        f32x4 v = s[q];
        #pragma unroll
        for (int j = 0; j < 4; j++) tl[lr][lc + q*4 + j] = v[j];
      }
    }
    __syncthreads();
    {
      const int oc = t >> 2, orr = (t & 3) * 16;
      if (qk){
        uint32_t w0 = pk4_e4m3(tl[orr+0][oc],  tl[orr+1][oc],  tl[orr+2][oc],  tl[orr+3][oc]);
        uint32_t w1 = pk4_e4m3(tl[orr+4][oc],  tl[orr+5][oc],  tl[orr+6][oc],  tl[orr+7][oc]);
        uint32_t w2 = pk4_e4m3(tl[orr+8][oc],  tl[orr+9][oc],  tl[orr+10][oc], tl[orr+11][oc]);
        uint32_t w3 = pk4_e4m3(tl[orr+12][oc], tl[orr+13][oc], tl[orr+14][oc], tl[orr+15][oc]);
        uint32_t* d = (uint32_t*)(WT8 + (long)(c0 + oc) * 768 + r0 + orr);
        d[0] = w0; d[1] = w1; d[2] = w2; d[3] = w3;
      } else {
        u16x8 o0, o1;
        #pragma unroll
        for (int i = 0; i < 8; i++){ o0[i] = f2bf(tl[orr + i][oc]); o1[i] = f2bf(tl[orr + 8 + i][oc]); }
        u16x8* dst = (u16x8*)(WpT + (long)(c0 + oc) * 768 + r0 + orr);
        dst[0] = o0; dst[1] = o1;
      }
    }
  } else {
    const long idx = ((long)(bx - 12720) * 256 + t) * 8;
    const int e = (int)(idx / 768), hd = (int)(idx - (long)e * 768);
    const float* s = wqkv + (long)e * 2304 + 1536 + hd;
    f32x4 a = *(const f32x4*)s, b = *(const f32x4*)(s + 4);
    u16x8 o;
    #pragma unroll
    for (int j = 0; j < 4; j++){ o[j] = f2bf(a[j]); o[4+j] = f2bf(b[j]); }
    *(u16x8*)(WvB + idx) = o;
  }
}

// ===================== fragment reads (conflict-free swizzle) ===============
static __device__ __forceinline__ bf16x8 ldfrag(const char* slot, int row, int ko){
  const int k2 = (ko ^ (row >> 1)) & 3;
  return *(const bf16x8*)(slot + row*64 + k2*16);
}
static __device__ __forceinline__ longx2 ldfrag8(const char* slot, int row, int ko){
  const int k2 = (ko ^ (row >> 1)) & 3;
  return *(const longx2*)(slot + row*64 + k2*16);
}

// ========== k_gemm256: fp8-input 256x256, 24-phase counted-vmcnt ============
static __device__ __forceinline__ void stg8(const unsigned char* __restrict__ G, int row0, int keB,
                                            char* lds_slot, int t){
  #pragma unroll
  for (int l = 0; l < 2; l++){
    const int r = l*128 + (t >> 2);
    const int c = (t & 3) ^ ((r >> 1) & 3);
    GLL((const char*)(G + (long)(row0 + r) * 768 + keB + c * 16),
        lds_slot + l*8192 + (t & 0x1C0) * 16);
  }
}

#define PH8(BUF, KK, MH, STAGE_STMT, WAIT_STMT) do {                           \
    longx2 af[4];                                                              \
    if (MH == 0) {                                                             \
      _Pragma("unroll")                                                        \
      for (int ni = 0; ni < 4; ni++)                                           \
        bq[ni] = ldfrag8(sB[BUF][KK], wn*64 + ni*16 + arow, ko);               \
    }                                                                          \
    _Pragma("unroll")                                                          \
    for (int mi = 0; mi < 4; mi++)                                             \
      af[mi] = ldfrag8(sA[BUF][KK], wm*128 + MH*64 + mi*16 + arow, ko);        \
    __builtin_amdgcn_s_barrier();                                              \
    __builtin_amdgcn_s_setprio(1);                                             \
    _Pragma("unroll")                                                          \
    for (int mi = 0; mi < 4; mi++)                                             \
      _Pragma("unroll")                                                        \
      for (int ni = 0; ni < 4; ni++){                                          \
        acc[MH*4+mi][ni] = __builtin_amdgcn_mfma_f32_16x16x32_fp8_fp8(         \
            af[mi][0], bq[ni][0], acc[MH*4+mi][ni], 0, 0, 0);                  \
        acc[MH*4+mi][ni] = __builtin_amdgcn_mfma_f32_16x16x32_fp8_fp8(         \
            af[mi][1], bq[ni][1], acc[MH*4+mi][ni], 0, 0, 0);                  \
      }                                                                        \
    __builtin_amdgcn_s_setprio(0);                                             \
    STAGE_STMT;                                                                \
    WAIT_STMT;                                                                 \
    __builtin_amdgcn_s_barrier();                                              \
  } while(0)

__global__ __launch_bounds__(512, 2)
void k_gemm256(const unsigned char* __restrict__ A8, const unsigned char* __restrict__ BT8,
               unsigned char* __restrict__ QT8, unsigned char* __restrict__ KT8,
               float* __restrict__ nrmp)
{
  __shared__ __attribute__((aligned(16))) char lds[131072];
  const int o  = blockIdx.x;
  const int wg = (o & 7) * 96 + (o >> 3);          // bijective XCD swizzle, 768 wgs
  const int jt = wg % 6, mt = wg / 6;
  const int m0 = mt * 256, j0 = jt * 256;
  const int t = threadIdx.x, lane = t & 63, w = t >> 6;
  const int wm = w >> 2, wn = w & 3;
  const int arow = lane & 15, ko = lane >> 4;

  char* const sA[2][2] = {{lds,           lds + 16384},
                          {lds + 65536,   lds + 65536 + 16384}};
  char* const sB[2][2] = {{lds + 32768,   lds + 49152},
                          {lds + 65536 + 32768, lds + 65536 + 49152}};

  f32x4 acc[8][4] = {};

  stg8(BT8, j0, 0,   sB[0][0], t);
  stg8(A8,  m0, 0,   sA[0][0], t);
  stg8(BT8, j0, 64,  sB[0][1], t);
  stg8(A8,  m0, 64,  sA[0][1], t);
  stg8(BT8, j0, 128, sB[1][0], t);
  stg8(A8,  m0, 128, sA[1][0], t);
  stg8(BT8, j0, 192, sB[1][1], t);
  asm volatile("s_waitcnt vmcnt(6)" ::: "memory");
  __builtin_amdgcn_s_barrier();

  #pragma unroll 1
  for (int it = 0; it < 3; ++it){
    const int t1 = 2*it + 1, t2 = 2*it + 2, t3 = 2*it + 3;
    longx2 bq[4];
    PH8(0,0,0, { stg8(A8, m0, t1*128+64, sA[1][1], t); }, ;);
    PH8(0,0,1, { if (t2 < 6) stg8(BT8, j0, t2*128,    sB[0][0], t); }, ;);
    PH8(0,1,0, { if (t2 < 6) stg8(A8,  m0, t2*128,    sA[0][0], t); }, ;);
    PH8(0,1,1, { if (t2 < 6) stg8(BT8, j0, t2*128+64, sB[0][1], t); },
               { if (it == 2) asm volatile("s_waitcnt vmcnt(0)" ::: "memory");
                 else         asm volatile("s_waitcnt vmcnt(6)" ::: "memory"); });
    PH8(1,0,0, { if (t2 < 6) stg8(A8,  m0, t2*128+64, sA[0][1], t); }, ;);
    PH8(1,0,1, { if (t3 < 6) stg8(BT8, j0, t3*128,    sB[1][0], t); }, ;);
    PH8(1,1,0, { if (t3 < 6) stg8(A8,  m0, t3*128,    sA[1][0], t); }, ;);
    PH8(1,1,1, { if (t3 < 6) stg8(BT8, j0, t3*128+64, sB[1][1], t); },
               { if (it == 2) asm volatile("s_waitcnt vmcnt(0)" ::: "memory");
                 else         asm volatile("s_waitcnt vmcnt(6)" ::: "memory"); });
  }

  const int b = m0 >> 12;
  const int chunk = ((m0 & 4095) >> 7) + wm;
  #pragma unroll
  for (int ni = 0; ni < 4; ni++){
    float ss = 0.f;
    #pragma unroll
    for (int mi = 0; mi < 8; mi++)
      #pragma unroll
      for (int r = 0; r < 4; r++) ss += acc[mi][ni][r] * acc[mi][ni][r];
    ss += __shfl_xor(ss, 16);
    ss += __shfl_xor(ss, 32);
    if (lane < 16){
      const int jc = j0 + wn*64 + ni*16 + lane;
      const int s  = (jc >= 768);
      const int jl = jc - s * 768;
      const int h  = jl / 48;
      const int c  = jl - h * 48;
      nrmp[(long)(s*6144 + (b*16 + h)*48 + c)*32 + chunk] = ss;
    }
  }
  #pragma unroll
  for (int mi = 0; mi < 8; mi++){
    #pragma unroll
    for (int ni = 0; ni < 4; ni++){
      const int j  = wn*64 + ni*16 + (lane & 15);
      const int nl = wm*128 + mi*16 + (lane >> 4)*4;
      uint32_t pk = pk4_e4m3(acc[mi][ni][0], acc[mi][ni][1], acc[mi][ni][2], acc[mi][ni][3]);
      const int d = (nl >> 2) ^ ((j & 15) << 2);
      *(uint32_t*)(lds + (long)j*256 + (d << 2)) = pk;
    }
  }
  __syncthreads();
  for (int rr = 0; rr < 32; rr++){
    const int j  = w*32 + rr;
    const int jc = j0 + j;
    const int s  = (jc >= 768);
    const int jl = jc - s * 768;
    const int h  = jl / 48;
    const int c  = jl - h * 48;
    const int dp = lane ^ ((j & 15) << 2);
    uint32_t v = *(const uint32_t*)(lds + (long)j*256 + (dp << 2));
    *(uint32_t*)((s ? KT8 : QT8) + ((long)((b*16 + h)*48 + c) << 12) + (m0 & 4095) + lane*4) = v;
  }
}

// =========== shared bf16 ring-3 machinery (gemmP / comb) ====================
static __device__ __forceinline__ void stageA512(const unsigned short* __restrict__ G, int row0, int ke,
                                                 char* slot, int t){
  const int r  = t >> 2;
  const int k2 = (t & 3) ^ ((r >> 1) & 3);
  GLL((const char*)(G + (long)(row0 + r) * 768 + ke + k2 * 8), slot + (t & 0x1C0) * 16);
}
static __device__ __forceinline__ void stageB512(const unsigned short* __restrict__ G, int row0, int ke,
                                                 char* slot, int t){
  #pragma unroll
  for (int l = 0; l < 2; l++){
    const int r  = l*128 + (t >> 2);
    const int k2 = (t & 3) ^ ((r >> 1) & 3);
    GLL((const char*)(G + (long)(row0 + r) * 768 + ke + k2 * 8), slot + l*8192 + (t & 0x1C0) * 16);
  }
}
// 256-thread stager for 128 rows (comb): 2 loads/thread
static __device__ __forceinline__ void stg128c(const unsigned short* __restrict__ G, int row0, int ke,
                                               char* slot, int t){
  #pragma unroll
  for (int l = 0; l < 2; l++){
    const int r  = ((l*4 + (t >> 6)) << 4) + ((t & 63) >> 2);
    const int k2 = (t & 3) ^ ((r >> 1) & 3);
    GLL((const char*)(G + (long)(row0 + r) * 768 + ke + k2 * 8),
        slot + l*4096 + (t & 0x3C0) * 16);
  }
}

#define VM0 asm volatile("s_waitcnt vmcnt(0)" ::: "memory")
#define VM3 asm volatile("s_waitcnt vmcnt(3)" ::: "memory")
#define VM4 asm volatile("s_waitcnt vmcnt(4)" ::: "memory")

#define PHASE1(CUR, STAGE_STMT, WAIT_STMT) do {                                \
    bf16x8 af[4], bq[4];                                                       \
    _Pragma("unroll")                                                          \
    for (int ni = 0; ni < 4; ni++)                                             \
      bq[ni] = ldfrag(sB[CUR], wn*64 + ni*16 + arow, ko);                      \
    _Pragma("unroll")                                                          \
    for (int mi = 0; mi < 4; mi++)                                             \
      af[mi] = ldfrag(sA[CUR], wm64 + mi*16 + arow, ko);                       \
    __builtin_amdgcn_s_barrier();                                              \
    __builtin_amdgcn_s_setprio(1);                                             \
    _Pragma("unroll")                                                          \
    for (int mi = 0; mi < 4; mi++)                                             \
      _Pragma("unroll")                                                        \
      for (int ni = 0; ni < 4; ni++)                                           \
        acc[mi][ni] = __builtin_amdgcn_mfma_f32_16x16x32_bf16(                 \
            af[mi], bq[ni], acc[mi][ni], 0, 0, 0);                             \
    __builtin_amdgcn_s_setprio(0);                                             \
    STAGE_STMT;                                                                \
    WAIT_STMT;                                                                 \
    __builtin_amdgcn_s_barrier();                                              \
  } while(0)

// ===== k_gemmP: 128x256 BK=32 ring-3 (proven), x_bf @ WcombT_b -> outF ======
__global__ __launch_bounds__(512, 4)
void k_gemmP(const unsigned short* __restrict__ A, const unsigned short* __restrict__ BT,
             float* __restrict__ OUTF, const float* __restrict__ bias)
{
  __shared__ __attribute__((aligned(16))) char lds[73728];
  const int o  = blockIdx.x;
  const int wg = (o & 7) * 96 + (o >> 3);                  // 768 wgs
  const int jt = wg % 3, mt = wg / 3;
  const int m0 = mt * 128, j0 = jt * 256;
  const int t = threadIdx.x, lane = t & 63, w = t >> 6;
  const int wm = w >> 2, wn = w & 3;
  const int wm64 = wm * 64;
  const int arow = lane & 15, ko = lane >> 4;
  const unsigned short* BTb = BT + ((long)(m0 >> 12)) * 589824;

  char* const sA[3] = {lds,          lds + 8192,          lds + 16384};
  char* const sB[3] = {lds + 24576,  lds + 24576 + 16384, lds + 24576 + 32768};

  f32x4 acc[4][4] = {};

  stageA512(A, m0, 0,  sA[0], t);  stageB512(BTb, j0, 0,  sB[0], t);
  stageA512(A, m0, 32, sA[1], t);  stageB512(BTb, j0, 32, sB[1], t);
  VM3;
  __builtin_amdgcn_s_barrier();

  #pragma unroll 1
  for (int g = 0; g < 7; ++g){
    const int kb = g * 96;
    PHASE1(0, { stageA512(A, m0, kb+64,  sA[2], t); stageB512(BTb, j0, kb+64,  sB[2], t); }, VM3);
    PHASE1(1, { stageA512(A, m0, kb+96,  sA[0], t); stageB512(BTb, j0, kb+96,  sB[0], t); }, VM3);
    PHASE1(2, { stageA512(A, m0, kb+128, sA[1], t); stageB512(BTb, j0, kb+128, sB[1], t); }, VM3);
  }
  PHASE1(0, { stageA512(A, m0, 736, sA[2], t); stageB512(BTb, j0, 736, sB[2], t); }, VM3);
  PHASE1(1, { ; }, VM0);
  PHASE1(2, { ; }, ;);

  #pragma unroll
  for (int mi = 0; mi < 4; mi++){
    #pragma unroll
    for (int ni = 0; ni < 4; ni++){
      const int jc = j0 + wn*64 + ni*16 + (lane & 15);
      const float bv = bias[jc];
      const long mr = (long)m0 + wm64 + mi*16 + (lane >> 4)*4;
      #pragma unroll
      for (int r = 0; r < 4; r++) OUTF[(mr + r) * 768 + jc] = acc[mi][ni][r] + bv;
    }
  }
}

// ------- S partials (fp8 MFMA): per (bh, ksp) 48x48 over 1024 n -------------
__global__ __launch_bounds__(256)
void k_attn_part(const unsigned char* __restrict__ QT8, const unsigned char* __restrict__ KT8,
                 float* __restrict__ Spart)
{
  __shared__ float Sl[4][2304];
  const int bh = blockIdx.x, ksp = blockIdx.y;
  const int t = threadIdx.x, lane = t & 63, w = t >> 6;
  const unsigned char* qb = QT8 + ((long)bh * 48 << 12);
  const unsigned char* kb = KT8 + ((long)bh * 48 << 12);
  const int n00 = ksp * 1024 + w * 256;
  f32x4 acc[3][3] = {};
  for (int kt = 0; kt < 256; kt += 32){
    long af[3], bfr[3];
    #pragma unroll
    for (int ci = 0; ci < 3; ci++)
      af[ci]  = *(const long*)(qb + ((long)(ci*16 + (lane & 15)) << 12) + n00 + kt + (lane >> 4) * 8);
    #pragma unroll
    for (int di = 0; di < 3; di++)
      bfr[di] = *(const long*)(kb + ((long)(di*16 + (lane & 15)) << 12) + n00 + kt + (lane >> 4) * 8);
    #pragma unroll
    for (int ci = 0; ci < 3; ci++)
      #pragma unroll
      for (int di = 0; di < 3; di++)
        acc[ci][di] = __builtin_amdgcn_mfma_f32_16x16x32_fp8_fp8(af[ci], bfr[di], acc[ci][di], 0, 0, 0);
  }
  #pragma unroll
  for (int ci = 0; ci < 3; ci++)
    #pragma unroll
    for (int di = 0; di < 3; di++)
      #pragma unroll
      for (int r = 0; r < 4; r++)
        Sl[w][(ci*16 + (lane >> 4)*4 + r) * 48 + di*16 + (lane & 15)] = acc[ci][di][r];
  __syncthreads();
  float* outp = Spart + ((long)ksp * 128 + bh) * 2304;
  for (int idx = t; idx < 2304; idx += 256)
    outp[idx] = Sl[0][idx] + Sl[1][idx] + Sl[2][idx] + Sl[3][idx];
}

// --- reduce partials + norms, scale, softmax -> attnT bf16 [bh][48 d][64 c] --
__global__ void k_softmax(const float* __restrict__ Spart, const float* __restrict__ nrmp,
                          const float* __restrict__ temp, unsigned short* __restrict__ attnT)
{
  __shared__ float invq[48], invk[48];
  const int bh = blockIdx.x, h = bh & 15;
  const int c = threadIdx.x;   // 64 threads, 48 active
  if (c < 48){
    float sq = 0.f, sk = 0.f;
    const float* pq = nrmp + (long)(bh*48 + c) * 32;
    const float* pk = nrmp + (long)(6144 + bh*48 + c) * 32;
    #pragma unroll
    for (int i = 0; i < 32; i++){ sq += pq[i]; sk += pk[i]; }
    invq[c] = 1.0f / fmaxf(sqrtf(sq), 1e-12f);
    invk[c] = 1.0f / fmaxf(sqrtf(sk), 1e-12f);
  }
  __syncthreads();
  if (c < 48){
    const float scq = invq[c] * temp[h];
    float row[48];
    #pragma unroll
    for (int d = 0; d < 48; d++){
      long base = ((long)bh * 48 + c) * 48 + d;
      float v = Spart[base] + Spart[base + 128L*2304] + Spart[base + 256L*2304] + Spart[base + 384L*2304];
      row[d] = v * scq * invk[d];
    }
    float mx = -1e30f;
    #pragma unroll
    for (int d = 0; d < 48; d++) mx = fmaxf(mx, row[d]);
    float s = 0.f;
    #pragma unroll
    for (int d = 0; d < 48; d++){ row[d] = expf(row[d] - mx); s += row[d]; }
    const float inv = 1.0f / s;
    unsigned short* ob = attnT + (long)bh * 48 * 64;
    #pragma unroll
    for (int d = 0; d < 48; d++) ob[d*64 + c] = f2bf(row[d] * inv);
    u16x8 z = {};
    *(u16x8*)(ob + c*64 + 48) = z;
    *(u16x8*)(ob + c*64 + 56) = z;
  }
}

// --- WmodT[b][j][h*48+d] = sum_c attnT[bh][d][c] * WpT[j][h*48+c] (MFMA) -----
__global__ __launch_bounds__(256)
void k_wmod2(const unsigned short* __restrict__ WpT, const unsigned short* __restrict__ attnT,
             unsigned short* __restrict__ WmodT)
{
  const int j0 = blockIdx.x * 256, h = blockIdx.y, b = blockIdx.z;
  const int t = threadIdx.x, lane = t & 63, w = t >> 6;
  const unsigned short* wp = WpT + h * 48;
  const unsigned short* ab = attnT + ((long)(b*16 + h)) * 48 * 64;
  f32x4 acc[4][3] = {};
  #pragma unroll
  for (int kt = 0; kt < 64; kt += 32){
    bf16x8 bfr[3];
    #pragma unroll
    for (int ni = 0; ni < 3; ni++)
      bfr[ni] = *(const bf16x8*)(ab + (ni*16 + (lane & 15))*64 + kt + (lane >> 4)*8);
    #pragma unroll
    for (int mi = 0; mi < 4; mi++){
      const int j = j0 + w*64 + mi*16 + (lane & 15);
      bf16x8 a = *(const bf16x8*)(wp + (long)j*768 + kt + (lane >> 4)*8);
      #pragma unroll
      for (int ni = 0; ni < 3; ni++)
        acc[mi][ni] = __builtin_amdgcn_mfma_f32_16x16x32_bf16(a, bfr[ni], acc[mi][ni], 0, 0, 0);
    }
  }
  #pragma unroll
  for (int mi = 0; mi < 4; mi++)
    #pragma unroll
    for (int ni = 0; ni < 3; ni++)
      #pragma unroll
      for (int r = 0; r < 4; r++){
        const int j = j0 + w*64 + mi*16 + (lane >> 4)*4 + r;
        const int d = ni*16 + (lane & 15);
        WmodT[(long)b*589824 + (long)j*768 + h*48 + d] = f2bf(acc[mi][ni][r]);
      }
}

// --- k_comb (ring-3): WcombT[row][e] = WmodT[row][hd] @ WvB[e][hd] ----------
__global__ __launch_bounds__(256, 3)
void k_comb(const unsigned short* __restrict__ A, const unsigned short* __restrict__ BT,
            unsigned short* __restrict__ OUT)
{
  __shared__ __attribute__((aligned(16))) char lds[49152];
  const int m0 = blockIdx.y * 128;
  const int j0 = blockIdx.x * 128;
  const int t = threadIdx.x, lane = t & 63, w = t >> 6;
  const int wm = w >> 1, wn = w & 1;
  const int wm64 = wm * 64;
  const int arow = lane & 15, ko = lane >> 4;

  char* const sA[3] = {lds,          lds + 8192,   lds + 16384};
  char* const sB[3] = {lds + 24576,  lds + 32768,  lds + 40960};

  f32x4 acc[4][4] = {};

  stg128c(A, m0, 0,  sA[0], t);  stg128c(BT, j0, 0,  sB[0], t);
  stg128c(A, m0, 32, sA[1], t);  stg128c(BT, j0, 32, sB[1], t);
  VM4;
  __builtin_amdgcn_s_barrier();

  #pragma unroll 1
  for (int g = 0; g < 7; ++g){
    const int kb = g * 96;
    PHASE1(0, { stg128c(A, m0, kb+64,  sA[2], t); stg128c(BT, j0, kb+64,  sB[2], t); }, VM4);
    PHASE1(1, { stg128c(A, m0, kb+96,  sA[0], t); stg128c(BT, j0, kb+96,  sB[0], t); }, VM4);
    PHASE1(2, { stg128c(A, m0, kb+128, sA[1], t); stg128c(BT, j0, kb+128, sB[1], t); }, VM4);
  }
  PHASE1(0, { stg128c(A, m0, 736, sA[2], t); stg128c(BT, j0, 736, sB[2], t); }, VM4);
  PHASE1(1, { ; }, VM0);
  PHASE1(2, { ; }, ;);

  #pragma unroll
  for (int mi = 0; mi < 4; mi++)
    #pragma unroll
    for (int ni = 0; ni < 4; ni++){
      const int jc = j0 + wn*64 + ni*16 + (lane & 15);
      const long mr = (long)m0 + wm64 + mi*16 + (lane >> 4) * 4;
      #pragma unroll
      for (int r = 0; r < 4; r++) OUT[(mr + r) * 768 + jc] = f2bf(acc[mi][ni][r]);
    }
}

extern "C" void kernel_launch(void* const* d_in, const int* in_sizes, int n_in,
                              void* d_out, int out_size, void* d_ws, size_t ws_size,
                              hipStream_t stream)
{
  (void)in_sizes; (void)n_in; (void)out_size; (void)ws_size;
  const float* x      = (const float*)d_in[0];
  const float* w_qkv  = (const float*)d_in[1];
  const float* temp   = (const float*)d_in[2];
  const float* w_proj = (const float*)d_in[3];
  const float* b_proj = (const float*)d_in[4];
  float* outF = (float*)d_out;

  char* ws = (char*)d_ws;
  size_t off = 0;
  auto alloc = [&](size_t bytes)->char*{ char* p = ws + off; off += (bytes + 255) & ~(size_t)255; return p; };

  unsigned short* x_bf  = (unsigned short*)alloc(50331648);           // [32768][768] bf16
  unsigned char*  x8    = (unsigned char*)alloc(25165824);            // [32768][768] e4m3
  unsigned char*  WT8   = (unsigned char*)alloc(1179648);             // [1536 q||k][768] e4m3
  unsigned short* WpT   = (unsigned short*)alloc(1179648);            // [768][768] bf16
  unsigned short* WvB   = (unsigned short*)alloc(1179648);            // [768 e][768 hd] bf16
  unsigned char*  QT8   = (unsigned char*)alloc(50331648);            // QT||KT [12288][4096] fp8
  unsigned char*  KT8   = QT8 + (long)6144 * 4096;
  float* nrmp           = (float*)alloc(12288L * 32 * 4);             // [12288 rows][32 chunks] f32
  float* Spart          = (float*)alloc(4L * 128 * 2304 * 4);         // [4][128][48][48] f32
  unsigned short* attnT = (unsigned short*)alloc(786432);             // [128][48 d][64 c] bf16
  unsigned short* WmodT = (unsigned short*)alloc(9437184);            // [8][768 j][768 hd] bf16
  unsigned short* WcombT= (unsigned short*)alloc(9437184);            // [8][768 j][768 e] bf16

  k_pre<<<13008, 256, 0, stream>>>(x, w_qkv, w_proj, x_bf, x8, WT8, WpT, WvB);
  k_gemm256<<<768, 512, 0, stream>>>(x8, WT8, QT8, KT8, nrmp);
  k_attn_part<<<dim3(128, 4), 256, 0, stream>>>(QT8, KT8, Spart);
  k_softmax<<<128, 64, 0, stream>>>(Spart, nrmp, temp, attnT);
  k_wmod2<<<dim3(3, 16, 8), 256, 0, stream>>>(WpT, attnT, WmodT);
  k_comb<<<dim3(6, 48), 256, 0, stream>>>(WmodT, WvB, WcombT);
  k_gemmP<<<768, 512, 0, stream>>>(x_bf, WcombT, outF, b_proj);
}

// Round 19
// 206.245 us; speedup vs baseline: 1.1285x; 1.0126x over previous
//
#include <hip/hip_runtime.h>
#include <stdint.h>

typedef __attribute__((ext_vector_type(4))) float          f32x4;
typedef __attribute__((ext_vector_type(8))) short          bf16x8;
typedef __attribute__((ext_vector_type(8))) unsigned short u16x8;
typedef __attribute__((ext_vector_type(4))) unsigned short u16x4;
typedef __attribute__((ext_vector_type(2))) long           longx2;

static __device__ __forceinline__ unsigned short f2bf(float f){
  uint32_t u = __builtin_bit_cast(uint32_t, f);
  u += 0x7FFFu + ((u >> 16) & 1u);          // RNE
  return (unsigned short)(u >> 16);
}

// ---- f32 -> OCP e4m3fn (software fallback; HW cvt_pk used when available) --
static __device__ __forceinline__ uint32_t f2e4m3(float x){
  uint32_t u = __builtin_bit_cast(uint32_t, x);
  uint32_t s = (u >> 24) & 0x80u;
  uint32_t a = u & 0x7FFFFFFFu;
  if (a >= 0x43E00000u) return s | 0x7Eu;
  int ebits = (int)(a >> 23);
  uint32_t mfull = (a & 0x7FFFFFu) | 0x800000u;
  int shift = (ebits >= 121) ? 20 : 20 + (121 - ebits);
  if (shift > 31) return s;
  uint32_t q = mfull >> shift;
  uint32_t rem = mfull & ((1u << shift) - 1u);
  uint32_t half = 1u << (shift - 1);
  q += (rem > half || (rem == half && (q & 1u)));
  if (ebits >= 121){
    uint32_t E = (uint32_t)(ebits - 121 + 1);
    if (q == 16u){ E += 1u; q = 8u; }
    uint32_t man = q - 8u;
    if (E > 15u || (E == 15u && man == 7u)) return s | 0x7Eu;
    return s | (E << 3) | man;
  } else {
    if (q >= 8u) return s | (1u << 3) | (q - 8u);
    return s | q;
  }
}
static __device__ __forceinline__ uint32_t pk4_e4m3(float a0, float a1, float a2, float a3){
#if __has_builtin(__builtin_amdgcn_cvt_pk_fp8_f32)
  uint32_t pk = (uint32_t)__builtin_amdgcn_cvt_pk_fp8_f32(a0, a1, 0, false);
  pk = (uint32_t)__builtin_amdgcn_cvt_pk_fp8_f32(a2, a3, (int)pk, true);
  return pk;
#else
  return f2e4m3(a0) | (f2e4m3(a1) << 8) | (f2e4m3(a2) << 16) | (f2e4m3(a3) << 24);
#endif
}

#define GLL(SRC, DST) __builtin_amdgcn_global_load_lds(                         \
    (const __attribute__((address_space(1))) unsigned int*)(SRC),               \
    (__attribute__((address_space(3))) unsigned int*)(DST), 16, 0, 0)

// ========== k_pre: merged preprocessing (cvt + tconv + cvtwv) ===============
__global__ void k_pre(const float* __restrict__ x, const float* __restrict__ wqkv,
                      const float* __restrict__ wproj,
                      unsigned short* __restrict__ xbf, unsigned char* __restrict__ x8,
                      unsigned char* __restrict__ WT8, unsigned short* __restrict__ WpT,
                      unsigned short* __restrict__ WvB)
{
  __shared__ float tl[64][65];
  const int bx = blockIdx.x, t = threadIdx.x;
  if (bx < 12288){
    const long i = ((long)bx * 256 + t) * 8;
    const f32x4* p = (const f32x4*)(x + i);
    f32x4 a = p[0], b = p[1];
    u16x8 o;
    #pragma unroll
    for (int j = 0; j < 4; j++){ o[j] = f2bf(a[j]); o[4+j] = f2bf(b[j]); }
    *(u16x8*)(xbf + i) = o;
    *(uint32_t*)(x8 + i)     = pk4_e4m3(a[0], a[1], a[2], a[3]);
    *(uint32_t*)(x8 + i + 4) = pk4_e4m3(b[0], b[1], b[2], b[3]);
  } else if (bx < 12720){
    const int idx = bx - 12288;
    const int cb = idx % 36, rb = idx / 36;
    const int qk = (cb < 24);
    const float* in = qk ? wqkv : wproj;
    const int C = qk ? 2304 : 768;
    const int c0 = (qk ? cb : cb - 24) * 64, r0 = rb * 64;
    {
      const int lr = t >> 2, lc = (t & 3) * 16;
      const f32x4* s = (const f32x4*)(in + (long)(r0 + lr) * C + c0 + lc);
      #pragma unroll
      for (int q = 0; q < 4; q++){
        f32x4 v = s[q];
        #pragma unroll
        for (int j = 0; j < 4; j++) tl[lr][lc + q*4 + j] = v[j];
      }
    }
    __syncthreads();
    {
      const int oc = t >> 2, orr = (t & 3) * 16;
      if (qk){
        uint32_t w0 = pk4_e4m3(tl[orr+0][oc],  tl[orr+1][oc],  tl[orr+2][oc],  tl[orr+3][oc]);
        uint32_t w1 = pk4_e4m3(tl[orr+4][oc],  tl[orr+5][oc],  tl[orr+6][oc],  tl[orr+7][oc]);
        uint32_t w2 = pk4_e4m3(tl[orr+8][oc],  tl[orr+9][oc],  tl[orr+10][oc], tl[orr+11][oc]);
        uint32_t w3 = pk4_e4m3(tl[orr+12][oc], tl[orr+13][oc], tl[orr+14][oc], tl[orr+15][oc]);
        uint32_t* d = (uint32_t*)(WT8 + (long)(c0 + oc) * 768 + r0 + orr);
        d[0] = w0; d[1] = w1; d[2] = w2; d[3] = w3;
      } else {
        u16x8 o0, o1;
        #pragma unroll
        for (int i = 0; i < 8; i++){ o0[i] = f2bf(tl[orr + i][oc]); o1[i] = f2bf(tl[orr + 8 + i][oc]); }
        u16x8* dst = (u16x8*)(WpT + (long)(c0 + oc) * 768 + r0 + orr);
        dst[0] = o0; dst[1] = o1;
      }
    }
  } else {
    const long idx = ((long)(bx - 12720) * 256 + t) * 8;
    const int e = (int)(idx / 768), hd = (int)(idx - (long)e * 768);
    const float* s = wqkv + (long)e * 2304 + 1536 + hd;
    f32x4 a = *(const f32x4*)s, b = *(const f32x4*)(s + 4);
    u16x8 o;
    #pragma unroll
    for (int j = 0; j < 4; j++){ o[j] = f2bf(a[j]); o[4+j] = f2bf(b[j]); }
    *(u16x8*)(WvB + idx) = o;
  }
}

// ===================== fragment reads (conflict-free swizzle) ===============
static __device__ __forceinline__ bf16x8 ldfrag(const char* slot, int row, int ko){
  const int k2 = (ko ^ (row >> 1)) & 3;
  return *(const bf16x8*)(slot + row*64 + k2*16);
}
static __device__ __forceinline__ longx2 ldfrag8(const char* slot, int row, int ko){
  const int k2 = (ko ^ (row >> 1)) & 3;
  return *(const longx2*)(slot + row*64 + k2*16);
}

// ========== k_gemm256: fp8-input 256x256, 24-phase counted-vmcnt ============
static __device__ __forceinline__ void stg8(const unsigned char* __restrict__ G, int row0, int keB,
                                            char* lds_slot, int t){
  #pragma unroll
  for (int l = 0; l < 2; l++){
    const int r = l*128 + (t >> 2);
    const int c = (t & 3) ^ ((r >> 1) & 3);
    GLL((const char*)(G + (long)(row0 + r) * 768 + keB + c * 16),
        lds_slot + l*8192 + (t & 0x1C0) * 16);
  }
}

#define PH8(BUF, KK, MH, STAGE_STMT, WAIT_STMT) do {                           \
    longx2 af[4];                                                              \
    if (MH == 0) {                                                             \
      _Pragma("unroll")                                                        \
      for (int ni = 0; ni < 4; ni++)                                           \
        bq[ni] = ldfrag8(sB[BUF][KK], wn*64 + ni*16 + arow, ko);               \
    }                                                                          \
    _Pragma("unroll")                                                          \
    for (int mi = 0; mi < 4; mi++)                                             \
      af[mi] = ldfrag8(sA[BUF][KK], wm*128 + MH*64 + mi*16 + arow, ko);        \
    __builtin_amdgcn_s_barrier();                                              \
    __builtin_amdgcn_s_setprio(1);                                             \
    _Pragma("unroll")                                                          \
    for (int mi = 0; mi < 4; mi++)                                             \
      _Pragma("unroll")                                                        \
      for (int ni = 0; ni < 4; ni++){                                          \
        acc[MH*4+mi][ni] = __builtin_amdgcn_mfma_f32_16x16x32_fp8_fp8(         \
            af[mi][0], bq[ni][0], acc[MH*4+mi][ni], 0, 0, 0);                  \
        acc[MH*4+mi][ni] = __builtin_amdgcn_mfma_f32_16x16x32_fp8_fp8(         \
            af[mi][1], bq[ni][1], acc[MH*4+mi][ni], 0, 0, 0);                  \
      }                                                                        \
    __builtin_amdgcn_s_setprio(0);                                             \
    STAGE_STMT;                                                                \
    WAIT_STMT;                                                                 \
    __builtin_amdgcn_s_barrier();                                              \
  } while(0)

__global__ __launch_bounds__(512, 2)
void k_gemm256(const unsigned char* __restrict__ A8, const unsigned char* __restrict__ BT8,
               unsigned char* __restrict__ QT8, unsigned char* __restrict__ KT8,
               float* __restrict__ nrmp)
{
  __shared__ __attribute__((aligned(16))) char lds[131072];
  const int o  = blockIdx.x;
  const int wg = (o & 7) * 96 + (o >> 3);          // bijective XCD swizzle, 768 wgs
  const int jt = wg % 6, mt = wg / 6;
  const int m0 = mt * 256, j0 = jt * 256;
  const int t = threadIdx.x, lane = t & 63, w = t >> 6;
  const int wm = w >> 2, wn = w & 3;
  const int arow = lane & 15, ko = lane >> 4;

  char* const sA[2][2] = {{lds,           lds + 16384},
                          {lds + 65536,   lds + 65536 + 16384}};
  char* const sB[2][2] = {{lds + 32768,   lds + 49152},
                          {lds + 65536 + 32768, lds + 65536 + 49152}};

  f32x4 acc[8][4] = {};

  stg8(BT8, j0, 0,   sB[0][0], t);
  stg8(A8,  m0, 0,   sA[0][0], t);
  stg8(BT8, j0, 64,  sB[0][1], t);
  stg8(A8,  m0, 64,  sA[0][1], t);
  stg8(BT8, j0, 128, sB[1][0], t);
  stg8(A8,  m0, 128, sA[1][0], t);
  stg8(BT8, j0, 192, sB[1][1], t);
  asm volatile("s_waitcnt vmcnt(6)" ::: "memory");
  __builtin_amdgcn_s_barrier();

  #pragma unroll 1
  for (int it = 0; it < 3; ++it){
    const int t1 = 2*it + 1, t2 = 2*it + 2, t3 = 2*it + 3;
    longx2 bq[4];
    PH8(0,0,0, { stg8(A8, m0, t1*128+64, sA[1][1], t); }, ;);
    PH8(0,0,1, { if (t2 < 6) stg8(BT8, j0, t2*128,    sB[0][0], t); }, ;);
    PH8(0,1,0, { if (t2 < 6) stg8(A8,  m0, t2*128,    sA[0][0], t); }, ;);
    PH8(0,1,1, { if (t2 < 6) stg8(BT8, j0, t2*128+64, sB[0][1], t); },
               { if (it == 2) asm volatile("s_waitcnt vmcnt(0)" ::: "memory");
                 else         asm volatile("s_waitcnt vmcnt(6)" ::: "memory"); });
    PH8(1,0,0, { if (t2 < 6) stg8(A8,  m0, t2*128+64, sA[0][1], t); }, ;);
    PH8(1,0,1, { if (t3 < 6) stg8(BT8, j0, t3*128,    sB[1][0], t); }, ;);
    PH8(1,1,0, { if (t3 < 6) stg8(A8,  m0, t3*128,    sA[1][0], t); }, ;);
    PH8(1,1,1, { if (t3 < 6) stg8(BT8, j0, t3*128+64, sB[1][1], t); },
               { if (it == 2) asm volatile("s_waitcnt vmcnt(0)" ::: "memory");
                 else         asm volatile("s_waitcnt vmcnt(6)" ::: "memory"); });
  }

  const int b = m0 >> 12;
  const int chunk = ((m0 & 4095) >> 7) + wm;
  #pragma unroll
  for (int ni = 0; ni < 4; ni++){
    float ss = 0.f;
    #pragma unroll
    for (int mi = 0; mi < 8; mi++)
      #pragma unroll
      for (int r = 0; r < 4; r++) ss += acc[mi][ni][r] * acc[mi][ni][r];
    ss += __shfl_xor(ss, 16);
    ss += __shfl_xor(ss, 32);
    if (lane < 16){
      const int jc = j0 + wn*64 + ni*16 + lane;
      const int s  = (jc >= 768);
      const int jl = jc - s * 768;
      const int h  = jl / 48;
      const int c  = jl - h * 48;
      nrmp[(long)(s*6144 + (b*16 + h)*48 + c)*32 + chunk] = ss;
    }
  }
  #pragma unroll
  for (int mi = 0; mi < 8; mi++){
    #pragma unroll
    for (int ni = 0; ni < 4; ni++){
      const int j  = wn*64 + ni*16 + (lane & 15);
      const int nl = wm*128 + mi*16 + (lane >> 4)*4;
      uint32_t pk = pk4_e4m3(acc[mi][ni][0], acc[mi][ni][1], acc[mi][ni][2], acc[mi][ni][3]);
      const int d = (nl >> 2) ^ ((j & 15) << 2);
      *(uint32_t*)(lds + (long)j*256 + (d << 2)) = pk;
    }
  }
  __syncthreads();
  for (int rr = 0; rr < 32; rr++){
    const int j  = w*32 + rr;
    const int jc = j0 + j;
    const int s  = (jc >= 768);
    const int jl = jc - s * 768;
    const int h  = jl / 48;
    const int c  = jl - h * 48;
    const int dp = lane ^ ((j & 15) << 2);
    uint32_t v = *(const uint32_t*)(lds + (long)j*256 + (dp << 2));
    *(uint32_t*)((s ? KT8 : QT8) + ((long)((b*16 + h)*48 + c) << 12) + (m0 & 4095) + lane*4) = v;
  }
}

// =========== shared bf16 ring-3 machinery (gemmP / comb) ====================
static __device__ __forceinline__ void stageA512(const unsigned short* __restrict__ G, int row0, int ke,
                                                 char* slot, int t){
  const int r  = t >> 2;
  const int k2 = (t & 3) ^ ((r >> 1) & 3);
  GLL((const char*)(G + (long)(row0 + r) * 768 + ke + k2 * 8), slot + (t & 0x1C0) * 16);
}
static __device__ __forceinline__ void stageB512(const unsigned short* __restrict__ G, int row0, int ke,
                                                 char* slot, int t){
  #pragma unroll
  for (int l = 0; l < 2; l++){
    const int r  = l*128 + (t >> 2);
    const int k2 = (t & 3) ^ ((r >> 1) & 3);
    GLL((const char*)(G + (long)(row0 + r) * 768 + ke + k2 * 8), slot + l*8192 + (t & 0x1C0) * 16);
  }
}
// 256-thread stager for 128 rows (comb): 2 loads/thread
static __device__ __forceinline__ void stg128c(const unsigned short* __restrict__ G, int row0, int ke,
                                               char* slot, int t){
  #pragma unroll
  for (int l = 0; l < 2; l++){
    const int r  = ((l*4 + (t >> 6)) << 4) + ((t & 63) >> 2);
    const int k2 = (t & 3) ^ ((r >> 1) & 3);
    GLL((const char*)(G + (long)(row0 + r) * 768 + ke + k2 * 8),
        slot + l*4096 + (t & 0x3C0) * 16);
  }
}

#define VM0 asm volatile("s_waitcnt vmcnt(0)" ::: "memory")
#define VM3 asm volatile("s_waitcnt vmcnt(3)" ::: "memory")
#define VM4 asm volatile("s_waitcnt vmcnt(4)" ::: "memory")

#define PHASE1(CUR, STAGE_STMT, WAIT_STMT) do {                                \
    bf16x8 af[4], bq[4];                                                       \
    _Pragma("unroll")                                                          \
    for (int ni = 0; ni < 4; ni++)                                             \
      bq[ni] = ldfrag(sB[CUR], wn*64 + ni*16 + arow, ko);                      \
    _Pragma("unroll")                                                          \
    for (int mi = 0; mi < 4; mi++)                                             \
      af[mi] = ldfrag(sA[CUR], wm64 + mi*16 + arow, ko);                       \
    __builtin_amdgcn_s_barrier();                                              \
    __builtin_amdgcn_s_setprio(1);                                             \
    _Pragma("unroll")                                                          \
    for (int mi = 0; mi < 4; mi++)                                             \
      _Pragma("unroll")                                                        \
      for (int ni = 0; ni < 4; ni++)                                           \
        acc[mi][ni] = __builtin_amdgcn_mfma_f32_16x16x32_bf16(                 \
            af[mi], bq[ni], acc[mi][ni], 0, 0, 0);                             \
    __builtin_amdgcn_s_setprio(0);                                             \
    STAGE_STMT;                                                                \
    WAIT_STMT;                                                                 \
    __builtin_amdgcn_s_barrier();                                              \
  } while(0)

// ===== k_gemmP: 128x256 BK=32 ring-3 (proven), x_bf @ WcombT_b -> outF ======
__global__ __launch_bounds__(512, 4)
void k_gemmP(const unsigned short* __restrict__ A, const unsigned short* __restrict__ BT,
             float* __restrict__ OUTF, const float* __restrict__ bias)
{
  __shared__ __attribute__((aligned(16))) char lds[73728];
  const int o  = blockIdx.x;
  const int wg = (o & 7) * 96 + (o >> 3);                  // 768 wgs
  const int jt = wg % 3, mt = wg / 3;
  const int m0 = mt * 128, j0 = jt * 256;
  const int t = threadIdx.x, lane = t & 63, w = t >> 6;
  const int wm = w >> 2, wn = w & 3;
  const int wm64 = wm * 64;
  const int arow = lane & 15, ko = lane >> 4;
  const unsigned short* BTb = BT + ((long)(m0 >> 12)) * 589824;

  char* const sA[3] = {lds,          lds + 8192,          lds + 16384};
  char* const sB[3] = {lds + 24576,  lds + 24576 + 16384, lds + 24576 + 32768};

  f32x4 acc[4][4] = {};

  stageA512(A, m0, 0,  sA[0], t);  stageB512(BTb, j0, 0,  sB[0], t);
  stageA512(A, m0, 32, sA[1], t);  stageB512(BTb, j0, 32, sB[1], t);
  VM3;
  __builtin_amdgcn_s_barrier();

  #pragma unroll 1
  for (int g = 0; g < 7; ++g){
    const int kb = g * 96;
    PHASE1(0, { stageA512(A, m0, kb+64,  sA[2], t); stageB512(BTb, j0, kb+64,  sB[2], t); }, VM3);
    PHASE1(1, { stageA512(A, m0, kb+96,  sA[0], t); stageB512(BTb, j0, kb+96,  sB[0], t); }, VM3);
    PHASE1(2, { stageA512(A, m0, kb+128, sA[1], t); stageB512(BTb, j0, kb+128, sB[1], t); }, VM3);
  }
  PHASE1(0, { stageA512(A, m0, 736, sA[2], t); stageB512(BTb, j0, 736, sB[2], t); }, VM3);
  PHASE1(1, { ; }, VM0);
  PHASE1(2, { ; }, ;);

  #pragma unroll
  for (int mi = 0; mi < 4; mi++){
    #pragma unroll
    for (int ni = 0; ni < 4; ni++){
      const int jc = j0 + wn*64 + ni*16 + (lane & 15);
      const float bv = bias[jc];
      const long mr = (long)m0 + wm64 + mi*16 + (lane >> 4)*4;
      #pragma unroll
      for (int r = 0; r < 4; r++) OUTF[(mr + r) * 768 + jc] = acc[mi][ni][r] + bv;
    }
  }
}

// ------- S partials (fp8 MFMA): per (bh, ksp) 48x48 over 2048 n -------------
__global__ __launch_bounds__(256)
void k_attn_part(const unsigned char* __restrict__ QT8, const unsigned char* __restrict__ KT8,
                 float* __restrict__ Spart)
{
  __shared__ float Sl[4][2304];
  const int bh = blockIdx.x, ksp = blockIdx.y;
  const int t = threadIdx.x, lane = t & 63, w = t >> 6;
  const unsigned char* qb = QT8 + ((long)bh * 48 << 12);
  const unsigned char* kb = KT8 + ((long)bh * 48 << 12);
  const int n00 = ksp * 2048 + w * 512;
  f32x4 acc[3][3] = {};
  for (int kt = 0; kt < 512; kt += 32){
    long af[3], bfr[3];
    #pragma unroll
    for (int ci = 0; ci < 3; ci++)
      af[ci]  = *(const long*)(qb + ((long)(ci*16 + (lane & 15)) << 12) + n00 + kt + (lane >> 4) * 8);
    #pragma unroll
    for (int di = 0; di < 3; di++)
      bfr[di] = *(const long*)(kb + ((long)(di*16 + (lane & 15)) << 12) + n00 + kt + (lane >> 4) * 8);
    #pragma unroll
    for (int ci = 0; ci < 3; ci++)
      #pragma unroll
      for (int di = 0; di < 3; di++)
        acc[ci][di] = __builtin_amdgcn_mfma_f32_16x16x32_fp8_fp8(af[ci], bfr[di], acc[ci][di], 0, 0, 0);
  }
  #pragma unroll
  for (int ci = 0; ci < 3; ci++)
    #pragma unroll
    for (int di = 0; di < 3; di++)
      #pragma unroll
      for (int r = 0; r < 4; r++)
        Sl[w][(ci*16 + (lane >> 4)*4 + r) * 48 + di*16 + (lane & 15)] = acc[ci][di][r];
  __syncthreads();
  float* outp = Spart + ((long)ksp * 128 + bh) * 2304;
  for (int idx = t; idx < 2304; idx += 256)
    outp[idx] = Sl[0][idx] + Sl[1][idx] + Sl[2][idx] + Sl[3][idx];
}

// ==== k_smw: softmax (-> attnT in LDS) + wmod, one block per bh =============
__global__ __launch_bounds__(256)
void k_smw(const float* __restrict__ Spart, const float* __restrict__ nrmp,
           const float* __restrict__ temp, const unsigned short* __restrict__ WpT,
           unsigned short* __restrict__ WmodT)
{
  __shared__ unsigned short aT[48 * 64];   // [48 d][64 c] bf16
  __shared__ float invq_s[48], invk_s[48];
  const int bh = blockIdx.x, h = bh & 15;
  const int t = threadIdx.x, lane = t & 63, w = t >> 6;
  if (t < 48){
    float sq = 0.f, sk = 0.f;
    const float* pq = nrmp + (long)(bh*48 + t) * 32;
    const float* pk = nrmp + (long)(6144 + bh*48 + t) * 32;
    #pragma unroll
    for (int i = 0; i < 32; i++){ sq += pq[i]; sk += pk[i]; }
    invq_s[t] = 1.0f / fmaxf(sqrtf(sq), 1e-12f);
    invk_s[t] = 1.0f / fmaxf(sqrtf(sk), 1e-12f);
  }
  __syncthreads();
  if (t < 48){
    const int c = t;
    const float scq = invq_s[c] * temp[h];
    float row[48];
    #pragma unroll
    for (int d = 0; d < 48; d++){
      long base = ((long)bh * 48 + c) * 48 + d;
      float v = Spart[base] + Spart[base + 128L*2304];
      row[d] = v * scq * invk_s[d];
    }
    float mx = -1e30f;
    #pragma unroll
    for (int d = 0; d < 48; d++) mx = fmaxf(mx, row[d]);
    float s = 0.f;
    #pragma unroll
    for (int d = 0; d < 48; d++){ row[d] = expf(row[d] - mx); s += row[d]; }
    const float inv = 1.0f / s;
    #pragma unroll
    for (int d = 0; d < 48; d++) aT[d*64 + c] = f2bf(row[d] * inv);
    u16x8 z = {};
    *(u16x8*)(aT + c*64 + 48) = z;
    *(u16x8*)(aT + c*64 + 56) = z;
  }
  __syncthreads();
  // wmod: wave w -> 192 j-rows in 3 chunks of 64
  const unsigned short* wp = WpT + h * 48;
  unsigned short* wmb = WmodT + (long)(bh >> 4) * 589824;
  #pragma unroll 1
  for (int ch = 0; ch < 3; ch++){
    f32x4 a2[4][3] = {};
    #pragma unroll
    for (int kt = 0; kt < 64; kt += 32){
      bf16x8 bfr2[3];
      #pragma unroll
      for (int ni = 0; ni < 3; ni++)
        bfr2[ni] = *(const bf16x8*)(aT + (ni*16 + (lane & 15))*64 + kt + (lane >> 4)*8);
      #pragma unroll
      for (int mi = 0; mi < 4; mi++){
        const int j = w*192 + ch*64 + mi*16 + (lane & 15);
        bf16x8 a = *(const bf16x8*)(wp + (long)j*768 + kt + (lane >> 4)*8);
        #pragma unroll
        for (int ni = 0; ni < 3; ni++)
          a2[mi][ni] = __builtin_amdgcn_mfma_f32_16x16x32_bf16(a, bfr2[ni], a2[mi][ni], 0, 0, 0);
      }
    }
    #pragma unroll
    for (int mi = 0; mi < 4; mi++)
      #pragma unroll
      for (int ni = 0; ni < 3; ni++)
        #pragma unroll
        for (int r = 0; r < 4; r++){
          const int j = w*192 + ch*64 + mi*16 + (lane >> 4)*4 + r;
          const int d = ni*16 + (lane & 15);
          wmb[(long)j*768 + h*48 + d] = f2bf(a2[mi][ni][r]);
        }
  }
}

// --- k_comb (ring-3): WcombT[row][e] = WmodT[row][hd] @ WvB[e][hd] ----------
__global__ __launch_bounds__(256, 3)
void k_comb(const unsigned short* __restrict__ A, const unsigned short* __restrict__ BT,
            unsigned short* __restrict__ OUT)
{
  __shared__ __attribute__((aligned(16))) char lds[49152];
  const int m0 = blockIdx.y * 128;
  const int j0 = blockIdx.x * 128;
  const int t = threadIdx.x, lane = t & 63, w = t >> 6;
  const int wm = w >> 1, wn = w & 1;
  const int wm64 = wm * 64;
  const int arow = lane & 15, ko = lane >> 4;

  char* const sA[3] = {lds,          lds + 8192,   lds + 16384};
  char* const sB[3] = {lds + 24576,  lds + 32768,  lds + 40960};

  f32x4 acc[4][4] = {};

  stg128c(A, m0, 0,  sA[0], t);  stg128c(BT, j0, 0,  sB[0], t);
  stg128c(A, m0, 32, sA[1], t);  stg128c(BT, j0, 32, sB[1], t);
  VM4;
  __builtin_amdgcn_s_barrier();

  #pragma unroll 1
  for (int g = 0; g < 7; ++g){
    const int kb = g * 96;
    PHASE1(0, { stg128c(A, m0, kb+64,  sA[2], t); stg128c(BT, j0, kb+64,  sB[2], t); }, VM4);
    PHASE1(1, { stg128c(A, m0, kb+96,  sA[0], t); stg128c(BT, j0, kb+96,  sB[0], t); }, VM4);
    PHASE1(2, { stg128c(A, m0, kb+128, sA[1], t); stg128c(BT, j0, kb+128, sB[1], t); }, VM4);
  }
  PHASE1(0, { stg128c(A, m0, 736, sA[2], t); stg128c(BT, j0, 736, sB[2], t); }, VM4);
  PHASE1(1, { ; }, VM0);
  PHASE1(2, { ; }, ;);

  #pragma unroll
  for (int mi = 0; mi < 4; mi++)
    #pragma unroll
    for (int ni = 0; ni < 4; ni++){
      const int jc = j0 + wn*64 + ni*16 + (lane & 15);
      const long mr = (long)m0 + wm64 + mi*16 + (lane >> 4) * 4;
      #pragma unroll
      for (int r = 0; r < 4; r++) OUT[(mr + r) * 768 + jc] = f2bf(acc[mi][ni][r]);
    }
}

extern "C" void kernel_launch(void* const* d_in, const int* in_sizes, int n_in,
                              void* d_out, int out_size, void* d_ws, size_t ws_size,
                              hipStream_t stream)
{
  (void)in_sizes; (void)n_in; (void)out_size; (void)ws_size;
  const float* x      = (const float*)d_in[0];
  const float* w_qkv  = (const float*)d_in[1];
  const float* temp   = (const float*)d_in[2];
  const float* w_proj = (const float*)d_in[3];
  const float* b_proj = (const float*)d_in[4];
  float* outF = (float*)d_out;

  char* ws = (char*)d_ws;
  size_t off = 0;
  auto alloc = [&](size_t bytes)->char*{ char* p = ws + off; off += (bytes + 255) & ~(size_t)255; return p; };

  unsigned short* x_bf  = (unsigned short*)alloc(50331648);           // [32768][768] bf16
  unsigned char*  x8    = (unsigned char*)alloc(25165824);            // [32768][768] e4m3
  unsigned char*  WT8   = (unsigned char*)alloc(1179648);             // [1536 q||k][768] e4m3
  unsigned short* WpT   = (unsigned short*)alloc(1179648);            // [768][768] bf16
  unsigned short* WvB   = (unsigned short*)alloc(1179648);            // [768 e][768 hd] bf16
  unsigned char*  QT8   = (unsigned char*)alloc(50331648);            // QT||KT [12288][4096] fp8
  unsigned char*  KT8   = QT8 + (long)6144 * 4096;
  float* nrmp           = (float*)alloc(12288L * 32 * 4);             // [12288 rows][32 chunks] f32
  float* Spart          = (float*)alloc(2L * 128 * 2304 * 4);         // [2][128][48][48] f32
  unsigned short* WmodT = (unsigned short*)alloc(9437184);            // [8][768 j][768 hd] bf16
  unsigned short* WcombT= (unsigned short*)alloc(9437184);            // [8][768 j][768 e] bf16

  k_pre<<<13008, 256, 0, stream>>>(x, w_qkv, w_proj, x_bf, x8, WT8, WpT, WvB);
  k_gemm256<<<768, 512, 0, stream>>>(x8, WT8, QT8, KT8, nrmp);
  k_attn_part<<<dim3(128, 2), 256, 0, stream>>>(QT8, KT8, Spart);
  k_smw<<<128, 256, 0, stream>>>(Spart, nrmp, temp, WpT, WmodT);
  k_comb<<<dim3(6, 48), 256, 0, stream>>>(WmodT, WvB, WcombT);
  k_gemmP<<<768, 512, 0, stream>>>(x_bf, WcombT, outF, b_proj);
}